// Round 1
// baseline (3550.002 us; speedup 1.0000x reference)
//
#include <hip/hip_runtime.h>
#include <hip/hip_bf16.h>

#define L_ 8
#define H_ 16
#define D_ 1024
#define HD_ 64
#define F_ 4096
#define B_ 2
#define S_ 2048
#define NTOK (B_*S_)

typedef unsigned short u16;
typedef __bf16 bf16x8 __attribute__((ext_vector_type(8)));
typedef float f32x4 __attribute__((ext_vector_type(4)));

__device__ __forceinline__ float b2f(u16 x){ union{unsigned u; float f;} c; c.u = ((unsigned)x)<<16; return c.f; }
__device__ __forceinline__ u16 f2b(float f){ union{float f; unsigned u;} c; c.f = f; unsigned u = c.u; return (u16)((u + 0x7fffu + ((u>>16)&1u)) >> 16); }

// ---------------- block reduce (256 threads, 4 waves) ----------------
__device__ __forceinline__ void blk_reduce2(float& a, float& b, float* sm){
  for (int off=32; off>0; off>>=1){ a += __shfl_down(a,off); b += __shfl_down(b,off); }
  int w = threadIdx.x>>6, ln = threadIdx.x&63;
  if (ln==0){ sm[w]=a; sm[4+w]=b; }
  __syncthreads();
  a = sm[0]+sm[1]+sm[2]+sm[3];
  b = sm[4]+sm[5]+sm[6]+sm[7];
}

// ---------------- embedding + LN -> x (f32) ----------------
__global__ __launch_bounds__(256) void embed_ln(const int* __restrict__ ids,
    const float* __restrict__ tok, const float* __restrict__ pos,
    const float* __restrict__ g, const float* __restrict__ bb,
    float* __restrict__ x)
{
  __shared__ float sm[8];
  int row = blockIdx.x;              // token index 0..NTOK-1
  int s   = row % S_;
  int id  = ids[row];
  const float* te = tok + (size_t)id * D_;
  const float* pe = pos + (size_t)s  * D_;
  float v[4]; float sum=0.f, sq=0.f;
  #pragma unroll
  for (int i=0;i<4;i++){ int d = threadIdx.x + i*256; v[i] = te[d] + pe[d]; sum += v[i]; sq += v[i]*v[i]; }
  blk_reduce2(sum, sq, sm);
  float mean = sum * (1.0f/D_);
  float var  = sq  * (1.0f/D_) - mean*mean;
  float inv  = rsqrtf(var + 1e-5f);
  #pragma unroll
  for (int i=0;i<4;i++){ int d = threadIdx.x + i*256; x[(size_t)row*D_ + d] = (v[i]-mean)*inv*g[d] + bb[d]; }
}

// ---------------- LN: x (f32) -> h (bf16) ----------------
__global__ __launch_bounds__(256) void ln_f32_bf16(const float* __restrict__ x,
    const float* __restrict__ g, const float* __restrict__ bb, u16* __restrict__ out)
{
  __shared__ float sm[8];
  int row = blockIdx.x;
  const float* xr = x + (size_t)row*D_;
  float v[4]; float sum=0.f, sq=0.f;
  #pragma unroll
  for (int i=0;i<4;i++){ int d = threadIdx.x + i*256; v[i] = xr[d]; sum += v[i]; sq += v[i]*v[i]; }
  blk_reduce2(sum, sq, sm);
  float mean = sum * (1.0f/D_);
  float var  = sq  * (1.0f/D_) - mean*mean;
  float inv  = rsqrtf(var + 1e-5f);
  #pragma unroll
  for (int i=0;i<4;i++){ int d = threadIdx.x + i*256; out[(size_t)row*D_ + d] = f2b((v[i]-mean)*inv*g[d] + bb[d]); }
}

// ---------------- generic transpose repack: src f32 [R][C] -> dst bf16 [C][R] ----------------
__global__ __launch_bounds__(256) void transpose_w(const float* __restrict__ src,
    u16* __restrict__ dst, int R, int C)
{
  __shared__ u16 tile[32][33];
  int c0 = blockIdx.x*32, r0 = blockIdx.y*32;
  int tx = threadIdx.x, ty = threadIdx.y;
  #pragma unroll
  for (int i=0;i<4;i++){
    int r = ty + i*8;
    tile[r][tx] = f2b(src[(size_t)(r0+r)*C + c0 + tx]);
  }
  __syncthreads();
  #pragma unroll
  for (int i=0;i<4;i++){
    int c = ty + i*8;
    dst[(size_t)(c0+c)*R + r0 + tx] = tile[tx][c];
  }
}

// ---------------- QKV weight repack: Wq/Wk/Wv [L][H][D][HD] f32 -> [3072][1024] bf16 (n=which*1024+h*64+hd, k=d)
__global__ __launch_bounds__(256) void qkv_repack(const float* __restrict__ Wq,
    const float* __restrict__ Wk, const float* __restrict__ Wv,
    u16* __restrict__ dst, int layer)
{
  __shared__ u16 tile[32][33];
  int z = blockIdx.z; int which = z >> 4, h = z & 15;
  const float* W = (which==0) ? Wq : (which==1) ? Wk : Wv;
  const float* src = W + ((size_t)(layer*H_ + h))*D_*HD_;   // [D][64]
  int d0 = blockIdx.x*32, c0 = blockIdx.y*32;
  int tx = threadIdx.x, ty = threadIdx.y;
  #pragma unroll
  for (int i=0;i<4;i++){
    int r = ty + i*8;
    tile[r][tx] = f2b(src[(size_t)(d0+r)*HD_ + c0 + tx]);
  }
  __syncthreads();
  #pragma unroll
  for (int i=0;i<4;i++){
    int hd = c0 + ty + i*8;
    dst[(size_t)(which*1024 + h*64 + hd)*D_ + d0 + tx] = tile[tx][ty + i*8];
  }
}

// ---------------- GEMM: C[M,N] = A[M,K](bf16) * Bt[N,K]^T (bf16), fused epilogues ----------------
// epi 0: obf = bf16(acc + bias)        (bias1!=null -> 3-way QKV bias select)
// epi 1: xres += acc + bias            (f32 residual)
// epi 2: obf = bf16(gelu(acc + bias))  (exact gelu)
__global__ __launch_bounds__(256) void gemm_bf16(
    const u16* __restrict__ A, const u16* __restrict__ Bt,
    const float* __restrict__ bias0, const float* __restrict__ bias1, const float* __restrict__ bias2,
    float* __restrict__ xres, u16* __restrict__ obf,
    int M, int N, int K, int epi)
{
  __shared__ u16 As[128*64];
  __shared__ u16 Bs[128*64];
  const int tid = threadIdx.x;
  const int bm = blockIdx.x * 128;
  const int bn = blockIdx.y * 128;
  const int wv = tid>>6, ln = tid&63;
  const int wr = wv>>1, wc = wv&1;
  const int l15 = ln&15, lhi = ln>>4;
  f32x4 acc[4][4];
  const f32x4 zero4 = {0.f,0.f,0.f,0.f};
  #pragma unroll
  for (int i=0;i<4;i++)
    #pragma unroll
    for (int j=0;j<4;j++) acc[i][j] = zero4;

  for (int k0 = 0; k0 < K; k0 += 64) {
    #pragma unroll
    for (int i=0;i<4;i++){
      int idx = tid + i*256;
      int row = idx>>3, c8 = idx&7;
      uint4 av = *(const uint4*)(A + (size_t)(bm+row)*K + k0 + c8*8);
      *(uint4*)(&As[row*64 + ((c8 ^ (row&7))<<3)]) = av;
      uint4 bv = *(const uint4*)(Bt + (size_t)(bn+row)*K + k0 + c8*8);
      *(uint4*)(&Bs[row*64 + ((c8 ^ (row&7))<<3)]) = bv;
    }
    __syncthreads();
    #pragma unroll
    for (int ks=0; ks<2; ks++){
      bf16x8 af[4], bfr[4];
      #pragma unroll
      for (int i=0;i<4;i++){
        int ra = wr*64 + i*16 + l15;
        af[i]  = *(const bf16x8*)(&As[ra*64 + (((ks*4+lhi) ^ (ra&7))<<3)]);
        int rb = wc*64 + i*16 + l15;
        bfr[i] = *(const bf16x8*)(&Bs[rb*64 + (((ks*4+lhi) ^ (rb&7))<<3)]);
      }
      #pragma unroll
      for (int i=0;i<4;i++)
        #pragma unroll
        for (int j=0;j<4;j++)
          acc[i][j] = __builtin_amdgcn_mfma_f32_16x16x32_bf16(af[i], bfr[j], acc[i][j], 0,0,0);
    }
    __syncthreads();
  }

  #pragma unroll
  for (int j=0;j<4;j++){
    int col = bn + wc*64 + j*16 + l15;
    float bval;
    if (bias1) bval = (col < 1024) ? bias0[col] : (col < 2048 ? bias1[col-1024] : bias2[col-2048]);
    else       bval = bias0[col];
    #pragma unroll
    for (int i=0;i<4;i++){
      int row0 = bm + wr*64 + i*16 + lhi*4;
      #pragma unroll
      for (int r=0;r<4;r++){
        float v = acc[i][j][r] + bval;
        size_t idx = (size_t)(row0+r)*N + col;
        if (epi==1)      xres[idx] += v;
        else if (epi==2) obf[idx] = f2b(0.5f*v*(1.0f + erff(v*0.70710678118f)));
        else             obf[idx] = f2b(v);
      }
    }
  }
}

// ---------------- flash attention ----------------
// qkv: [NTOK][3072] bf16 (q|k|v each [H][64] per token). att out: [NTOK][1024] bf16.
__global__ __launch_bounds__(256) void attn_fwd(const u16* __restrict__ qkv, u16* __restrict__ att)
{
  __shared__ u16 Ks[64*64];
  __shared__ u16 Vt[64*64];
  __shared__ u16 Ps[4][16*64];
  const int qt = blockIdx.x, h = blockIdx.y, b = blockIdx.z;
  const int tid = threadIdx.x, wv = tid>>6, ln = tid&63, l15 = ln&15, lhi = ln>>4;
  const int RS = 3*D_;  // 3072
  const u16* base = qkv + (size_t)b*S_*RS + h*HD_;
  const u16* qg = base;
  const u16* kg = base + D_;
  const u16* vg = base + 2*D_;
  const float SCALE = 0.125f;

  bf16x8 qf[2];
  {
    const u16* qrow = qg + (size_t)(qt*64 + wv*16 + l15)*RS;
    qf[0] = *(const bf16x8*)(qrow + lhi*8);
    qf[1] = *(const bf16x8*)(qrow + 32 + lhi*8);
  }
  const f32x4 zero4 = {0.f,0.f,0.f,0.f};
  f32x4 oacc[4];
  #pragma unroll
  for (int j=0;j<4;j++) oacc[j] = zero4;
  float m[4], lsum[4];
  #pragma unroll
  for (int r=0;r<4;r++){ m[r] = -1e30f; lsum[r] = 0.f; }

  for (int kt=0; kt<S_/64; kt++){
    __syncthreads();
    #pragma unroll
    for (int i=0;i<2;i++){
      int idx = tid + i*256;
      int row = idx>>3, c8 = idx&7;
      uint4 kvv = *(const uint4*)(kg + (size_t)(kt*64+row)*RS + c8*8);
      *(uint4*)(&Ks[row*64 + ((c8 ^ (row&7))<<3)]) = kvv;
      uint4 vvv = *(const uint4*)(vg + (size_t)(kt*64+row)*RS + c8*8);
      const u16* vs = (const u16*)&vvv;
      #pragma unroll
      for (int j=0;j<8;j++){
        int d = c8*8 + j;
        Vt[d*64 + (row ^ ((d&7)<<3))] = vs[j];
      }
    }
    __syncthreads();

    // S = Q K^T  (rows q = lhi*4+r, cols key = j*16+l15)
    f32x4 s[4];
    #pragma unroll
    for (int j=0;j<4;j++){
      s[j] = zero4;
      #pragma unroll
      for (int ks=0; ks<2; ks++){
        int kr = j*16 + l15;
        bf16x8 kf = *(const bf16x8*)(&Ks[kr*64 + (((ks*4+lhi) ^ (kr&7))<<3)]);
        s[j] = __builtin_amdgcn_mfma_f32_16x16x32_bf16(qf[ks], kf, s[j], 0,0,0);
      }
    }
    // online softmax
    float rmax[4];
    #pragma unroll
    for (int r=0;r<4;r++)
      rmax[r] = fmaxf(fmaxf(s[0][r], s[1][r]), fmaxf(s[2][r], s[3][r]));
    #pragma unroll
    for (int msk=1; msk<16; msk<<=1)
      #pragma unroll
      for (int r=0;r<4;r++) rmax[r] = fmaxf(rmax[r], __shfl_xor(rmax[r], msk));
    float corr[4], rsum[4];
    #pragma unroll
    for (int r=0;r<4;r++){
      float mn = fmaxf(m[r], rmax[r]);
      corr[r] = __expf(SCALE*(m[r]-mn));
      m[r] = mn; rsum[r] = 0.f;
    }
    #pragma unroll
    for (int j=0;j<4;j++){
      #pragma unroll
      for (int r=0;r<4;r++){
        float p = __expf(SCALE*(s[j][r]-m[r]));
        rsum[r] += p;
        int q = lhi*4 + r, key = j*16 + l15;
        Ps[wv][q*64 + (key ^ ((q&7)<<3))] = f2b(p);
      }
    }
    #pragma unroll
    for (int msk=1; msk<16; msk<<=1)
      #pragma unroll
      for (int r=0;r<4;r++) rsum[r] += __shfl_xor(rsum[r], msk);
    #pragma unroll
    for (int r=0;r<4;r++) lsum[r] = lsum[r]*corr[r] + rsum[r];
    #pragma unroll
    for (int j=0;j<4;j++)
      #pragma unroll
      for (int r=0;r<4;r++) oacc[j][r] *= corr[r];

    __syncthreads();  // make Ps writes visible / ordered before fragment reads

    // O += P V   (A-frag from Ps, B-frag from Vt)
    bf16x8 pf[2];
    pf[0] = *(const bf16x8*)(&Ps[wv][l15*64 + ((lhi ^ (l15&7))<<3)]);
    pf[1] = *(const bf16x8*)(&Ps[wv][l15*64 + (((4+lhi) ^ (l15&7))<<3)]);
    #pragma unroll
    for (int dj=0; dj<4; dj++){
      #pragma unroll
      for (int ks=0; ks<2; ks++){
        int vr = dj*16 + l15;
        bf16x8 vf = *(const bf16x8*)(&Vt[vr*64 + (((ks*4+lhi) ^ (vr&7))<<3)]);
        oacc[dj] = __builtin_amdgcn_mfma_f32_16x16x32_bf16(pf[ks], vf, oacc[dj], 0,0,0);
      }
    }
  }
  // epilogue: att[token][h*64 + d]
  #pragma unroll
  for (int dj=0; dj<4; dj++){
    #pragma unroll
    for (int r=0;r<4;r++){
      int q = lhi*4 + r;
      int token = qt*64 + wv*16 + q;
      float val = oacc[dj][r] / lsum[r];
      att[(size_t)(b*S_ + token)*D_ + h*HD_ + dj*16 + l15] = f2b(val);
    }
  }
}

// ---------------- orchestration ----------------
extern "C" void kernel_launch(void* const* d_in, const int* in_sizes, int n_in,
                              void* d_out, int out_size, void* d_ws, size_t ws_size,
                              hipStream_t stream)
{
  const int*   ids   = (const int*)d_in[0];
  const float* tok   = (const float*)d_in[1];
  const float* pos   = (const float*)d_in[2];
  const float* emb_g = (const float*)d_in[3];
  const float* emb_b = (const float*)d_in[4];
  const float* ln1g  = (const float*)d_in[5];
  const float* ln1b  = (const float*)d_in[6];
  const float* ln2g  = (const float*)d_in[7];
  const float* ln2b  = (const float*)d_in[8];
  const float* Wq = (const float*)d_in[9];
  const float* bq = (const float*)d_in[10];
  const float* Wk = (const float*)d_in[11];
  const float* bk = (const float*)d_in[12];
  const float* Wv = (const float*)d_in[13];
  const float* bv = (const float*)d_in[14];
  const float* Wo = (const float*)d_in[15];
  const float* bo = (const float*)d_in[16];
  const float* W1 = (const float*)d_in[17];
  const float* b1 = (const float*)d_in[18];
  const float* W2 = (const float*)d_in[19];
  const float* b2 = (const float*)d_in[20];

  float* x = (float*)d_out;                    // residual stream lives in d_out (f32)
  char* ws = (char*)d_ws;
  u16* h     = (u16*)(ws);                     //  8,388,608 B
  u16* qkvb  = (u16*)(ws + 8388608);           // 25,165,824 B
  u16* att   = (u16*)(ws + 33554432);          //  8,388,608 B
  u16* fbuf  = (u16*)(ws + 41943040);          // 33,554,432 B
  u16* wqkvt = (u16*)(ws + 75497472);          //  6,291,456 B
  u16* wot   = (u16*)(ws + 81788928);          //  2,097,152 B
  u16* w1t   = (u16*)(ws + 83886080);          //  8,388,608 B
  u16* w2t   = (u16*)(ws + 92274688);          //  8,388,608 B  (end ~96 MB)

  embed_ln<<<NTOK, 256, 0, stream>>>(ids, tok, pos, emb_g, emb_b, x);

  for (int l=0; l<L_; l++){
    ln_f32_bf16<<<NTOK, 256, 0, stream>>>(x, ln1g + l*D_, ln1b + l*D_, h);
    qkv_repack<<<dim3(32,2,48), dim3(32,8), 0, stream>>>(Wq, Wk, Wv, wqkvt, l);
    gemm_bf16<<<dim3(32,24), 256, 0, stream>>>(h, wqkvt,
        bq + l*1024, bk + l*1024, bv + l*1024,
        nullptr, qkvb, NTOK, 3072, 1024, 0);
    attn_fwd<<<dim3(S_/64, H_, B_), 256, 0, stream>>>(qkvb, att);
    transpose_w<<<dim3(32,32), dim3(32,8), 0, stream>>>(Wo + (size_t)l*D_*D_, wot, D_, D_);
    gemm_bf16<<<dim3(32,8), 256, 0, stream>>>(att, wot,
        bo + l*D_, nullptr, nullptr,
        x, nullptr, NTOK, 1024, 1024, 1);
    ln_f32_bf16<<<NTOK, 256, 0, stream>>>(x, ln2g + l*D_, ln2b + l*D_, h);
    transpose_w<<<dim3(128,32), dim3(32,8), 0, stream>>>(W1 + (size_t)l*D_*F_, w1t, D_, F_);
    gemm_bf16<<<dim3(32,32), 256, 0, stream>>>(h, w1t,
        b1 + l*F_, nullptr, nullptr,
        nullptr, fbuf, NTOK, 4096, 1024, 2);
    transpose_w<<<dim3(32,128), dim3(32,8), 0, stream>>>(W2 + (size_t)l*F_*D_, w2t, F_, D_);
    gemm_bf16<<<dim3(32,8), 256, 0, stream>>>(fbuf, w2t,
        b2 + l*D_, nullptr, nullptr,
        x, nullptr, NTOK, 1024, 4096, 1);
  }
}